// Round 5
// baseline (59.548 us; speedup 1.0000x reference)
//
#include <hip/hip_runtime.h>
#include <hip/hip_bf16.h>

// Decoder: preds[s,b] = hidden[s,b,:] @ W[0] + b[0]  (S=4096, B=64, H=256)
// loss = sum((preds - outputs.T)^2); d_out = [loss, preds.reshape(-1)]
//
// Memory-bound: hidden = 256 MiB f32 read once -> HBM floor ~41-44 us.
// R4: single kernel. Loss via one f32 atomicAdd per block into out[0]
// (zeroed by a 4-byte memset graph node) -- removes the dependent
// 1-block reduce kernel (~5-7 us of serialized dispatch+execution).
// Body identical to R3: wave owns 32 consecutive rows, blocked loads,
// coalesced 128B pred store, outputs gather is L2-resident.

constexpr int S = 4096;
constexpr int B = 64;
constexpr int H = 256;
constexpr int P = S * B;            // 262144 rows
constexpr int BLOCK = 256;          // 4 waves/block
constexpr int GRID = 2048;          // 8192 waves * 32 rows/wave = P exactly

__global__ __launch_bounds__(BLOCK, 4) void decoder_main(
    const float* __restrict__ outputs,   // [B, S]
    const float* __restrict__ hidden,    // [S, B, H]
    const float* __restrict__ W,         // [1, H]
    const float* __restrict__ bias,      // [1]
    float* __restrict__ out)             // [1 + P]: out[0]=loss (pre-zeroed)
{
    const int tid  = threadIdx.x;
    const int lane = tid & 63;
    const int sub  = lane >> 4;          // row subgroup (0..3)
    const int l16  = lane & 15;          // lane within 16-lane row group
    const int gwave = (blockIdx.x * BLOCK + tid) >> 6;   // 0..8191
    const int base  = gwave * 32;        // this wave's 32 consecutive rows

    // Blocked W ownership: lane owns cols [l16*16, l16*16+16).
    const float4* W4 = reinterpret_cast<const float4*>(W) + l16 * 4;
    const float4 w0 = W4[0], w1 = W4[1], w2 = W4[2], w3 = W4[3];
    const float b0 = bias[0];

    // Lane L (<32) ends holding the dot for row base+L:
    // produced at iteration t = L>>2 by subgroup L&3.
    const int tsel = lane >> 2;
    const int gsel = (lane & 3) << 4;    // a lane inside subgroup (L&3)

    float my_dot = 0.0f;

    #pragma unroll
    for (int t = 0; t < 8; ++t) {
        const int p = base + 4 * t + sub;
        const float4* hp =
            reinterpret_cast<const float4*>(hidden + (size_t)p * H) + l16 * 4;
        const float4 h0 = hp[0], h1 = hp[1], h2 = hp[2], h3 = hp[3];

        float d = h0.x * w0.x + h0.y * w0.y + h0.z * w0.z + h0.w * w0.w;
        d += h1.x * w1.x + h1.y * w1.y + h1.z * w1.z + h1.w * w1.w;
        d += h2.x * w2.x + h2.y * w2.y + h2.z * w2.z + h2.w * w2.w;
        d += h3.x * w3.x + h3.y * w3.y + h3.z * w3.z + h3.w * w3.w;

        // Reduce within each 16-lane group (row dot, broadcast to group).
        #pragma unroll
        for (int off = 1; off < 16; off <<= 1)
            d += __shfl_xor(d, off, 64);

        // Gather: lane L grabs subgroup (L&3)'s dot; keeps it if t == L>>2.
        const float g = __shfl(d, gsel, 64);
        if (t == tsel) my_dot = g;
    }

    // Epilogue: coalesced pred store + loss contribution (lanes 0..31).
    float se = 0.0f;
    if (lane < 32) {
        const float pred = my_dot + b0;
        out[1 + base + lane] = pred;               // 128B contiguous store
        const int s_idx = base >> 6;               // same s for all 32 rows
        const int bb    = (base & 63) + lane;      // bb in [0,64)
        const float diff = pred - outputs[bb * S + s_idx];  // L2-resident gather
        se = diff * diff;
    }

    // Wave then block reduce; ONE atomic per block (2048 total, no contention).
    #pragma unroll
    for (int off = 32; off > 0; off >>= 1)
        se += __shfl_xor(se, off, 64);

    __shared__ float lsum[BLOCK / 64];
    if (lane == 0) lsum[tid >> 6] = se;
    __syncthreads();
    if (tid == 0) {
        atomicAdd(out, lsum[0] + lsum[1] + lsum[2] + lsum[3]);
    }
}

extern "C" void kernel_launch(void* const* d_in, const int* in_sizes, int n_in,
                              void* d_out, int out_size, void* d_ws, size_t ws_size,
                              hipStream_t stream) {
    const float* outputs = (const float*)d_in[0];  // [B, S]
    const float* hidden  = (const float*)d_in[1];  // [S, B, H]
    const float* W       = (const float*)d_in[2];  // [1, H]
    const float* bias    = (const float*)d_in[3];  // [1]
    float* out = (float*)d_out;                    // [1 + S*B]

    // out[0] is the atomic loss accumulator; must start at 0 every replay
    // (harness does not re-poison between replays).
    hipMemsetAsync(out, 0, sizeof(float), stream);

    decoder_main<<<GRID, BLOCK, 0, stream>>>(outputs, hidden, W, bias, out);
}